// Round 17
// baseline (260.656 us; speedup 1.0000x reference)
//
#include <hip/hip_runtime.h>

typedef unsigned char u8;
typedef float f32x4 __attribute__((ext_vector_type(4)));
typedef float f4u __attribute__((ext_vector_type(4), aligned(4)));  // dword-aligned float4

#define P_OUT 29791      // 31^3
#define NCH   512

// ---- pack 4 fp32 -> 4 fp8 e4m3 (RNE, OCP) ----
__device__ __forceinline__ unsigned pk4_fp8(float a, float b, float c, float d) {
  int v = __builtin_amdgcn_cvt_pk_fp8_f32(a, b, 0, false);   // low word
  v = __builtin_amdgcn_cvt_pk_fp8_f32(c, d, v, true);        // high word
  return (unsigned)v;
}

// ---- w-prep: 512 rows, 16 rows/block, 32 blocks ----
__global__ void wprep_kernel(const float* __restrict__ w,
                             u8* __restrict__ wb, float* __restrict__ wsq) {
  const int tid = threadIdx.x;
  const int g = blockIdx.x * 16 + (tid >> 4);  // 0..511
  const int c = tid & 15;
  const float4* wr = (const float4*)(w + g * 128 + c * 8);
  float4 f0 = wr[0], f1 = wr[1];
  float s = f0.x*f0.x + f0.y*f0.y + f0.z*f0.z + f0.w*f0.w
          + f1.x*f1.x + f1.y*f1.y + f1.z*f1.z + f1.w*f1.w;
#pragma unroll
  for (int m = 1; m < 16; m <<= 1) s += __shfl_xor(s, m, 64);
  uint2 pk;
  pk.x = pk4_fp8(f0.x, f0.y, f0.z, f0.w);
  pk.y = pk4_fp8(f1.x, f1.y, f1.z, f1.w);
  *(uint2*)(wb + g * 128 + c * 8) = pk;
  if (c == 0) wsq[g] = s;
}

// async global->LDS, 16 B per lane, lands at ldsbase + lane*16
#define GLDS(g, l) __builtin_amdgcn_global_load_lds(                         \
    (const __attribute__((address_space(1))) unsigned int*)(g),              \
    (__attribute__((address_space(3))) unsigned int*)(l), 16, 0, 0)

// lgkm-only barrier: orders LDS ops across waves WITHOUT draining vmcnt.
#define LGKM_BAR() do {                                                      \
    asm volatile("s_waitcnt lgkmcnt(0)\n\ts_barrier" ::: "memory");          \
    __builtin_amdgcn_sched_barrier(0);                                       \
  } while (0)

// counted-vmcnt barrier (T4): waits until <=16 VMEM ops outstanding.
// In-order retirement: any op with >=16 younger VMEM ops (the Ws
// prefetch has 32: 16 wsq loads + 16 stores) is forced complete while
// the newest stores stay in flight. Stores are NEVER drained to 0.
#define VMC_BAR() do {                                                       \
    asm volatile("s_waitcnt vmcnt(16)\n\ts_barrier" ::: "memory");           \
    __builtin_amdgcn_sched_barrier(0);                                       \
  } while (0)

// ---- Fused unfold + GEMM, ct-loop pipeline, 3-blocks/CU LDS diet ----
// r16 structure; two LDS cuts unlock 3 blocks/CU (was 2, and r15 measured
// Occupancy 16.7% + latency-bound signature -> residency is the lever):
//  (1) Xs stride back to 320 (r14's 328 pad measured null): 20,480 B.
//  (2) Ep shrunk to [32][132] f32 (16.9 KB), epilogue in 4 passes of 32
//      ch-rows (pass q = acc i-index; q2=q>>1 (was pa), q1=q&1 (was ii)),
//      living entirely in the dead Xs region.
// SMEM = 32 KB Ws dbuf + 20 KB (Xs|Ep) = 53,248 B -> 3 blocks/CU.
// One block per (nb, d, hb): grid 992 = 8*124 bijective XCD chunking;
// Xs staged ONCE, B packed ONCE into 32 VGPRs; ct = 0..3 with dbuf'd Ws
// (prefetch ct+2 after post-MFMA lgkm bar; completion via VMC_BAR).
__global__ __launch_bounds__(256, 2)
void gauss_fused_kernel(const float* __restrict__ x,
                        const u8* __restrict__ wb,
                        const float* __restrict__ wsq,
                        float* __restrict__ out) {
  __shared__ __align__(16) u8 SMEM[53248];
  u8* Ws0 = SMEM;                       // w tile buf 0, 16 KB
  u8* Ws1 = SMEM + 16384;               // w tile buf 1, 16 KB
  float* Xs = (float*)(SMEM + 32768);   // x slab [16c][320], 20 KB (prologue)
  float* Ep = (float*)(SMEM + 32768);   // epilogue [32][132] f32 (ct loop)

  const int bid = blockIdx.x;
  const int tile = (bid & 7) * 124 + (bid >> 3);   // bijective XCD chunking
  const unsigned nb = (unsigned)tile / 248u;       // 4 batches
  const unsigned r2 = (unsigned)tile - nb * 248u;
  const unsigned d  = r2 >> 3;                     // 31 d values
  const unsigned hb = r2 & 7;                      // 8 h-blocks, fastest
  const int h0 = hb * 4;
  const int nh = (h0 + 4 <= 31) ? 4 : (31 - h0);   // 4 (hb<7) or 3 (hb=7)
  const int nrows = nh * 31;                       // 124 or 93
  const int tp0 = d * 961 + h0 * 31;               // tile's base p

  const int tid = threadIdx.x;
  const int wid = tid >> 6;
  const int lane = tid & 63;
  const int quad = lane >> 4;
  const int col = lane & 15;
  const int wch = wid & 1;   // wave ch-half
  const int wp = wid >> 1;   // wave p-half

  // ---- stage Ws0 (ct=0, channels 0-127): 1024 swizzled chunks ----
#pragma unroll
  for (int t = 0; t < 4; ++t) {
    const int Lb = (wid * 4 + t) * 64;
    const int L = Lb + lane;
    const int row = L >> 3;
    const int jc = (L & 7) ^ (row & 7);
    GLDS(wb + (size_t)row * 128 + jc * 16, &Ws0[Lb * 16]);
  }

  // ---- stage x slab [16c][2kd][5hq][32w]: 1280 chunks, 5 rounds ----
#pragma unroll
  for (int t = 0; t < 5; ++t) {
    const int Lb = t * 256 + wid * 64;
    const int L = Lb + lane;
    const int row = L >> 3;                // 0..159
    const int jc = L & 7;
    const unsigned c = (unsigned)row / 10u;
    const unsigned rr = (unsigned)row - c * 10u;
    const unsigned kd = rr / 5u;
    const unsigned hq = rr - kd * 5u;
    const int hg = h0 + (int)hq;
    const int hcl = (hg < 31) ? hg : 31;   // hb=7 tail slot, unused
    GLDS(x + (((size_t)(nb * 16 + c)) << 15) + (d + kd) * 1024 + hcl * 32 + jc * 4,
         &Xs[Lb * 4]);
  }

  // ---- per-lane p-row decode (hides under GLDS flight) ----
  int rb[4];
  int xoff[4];
#pragma unroll
  for (int j = 0; j < 4; ++j) {
    rb[j] = wp * 64 + j * 16 + col;
    const unsigned rc = (unsigned)((rb[j] < nrows) ? rb[j] : (nrows - 1));
    const unsigned hh = rc / 31u;
    const unsigned wv = rc - hh * 31u;
    xoff[j] = (int)(hh * 32 + wv);
  }

  __syncthreads();   // block start: drains Ws0 + Xs (no stores pending)

  // ---- prefetch Ws1 (ct=1, channels 128-255); flies under the pack ----
#pragma unroll
  for (int t = 0; t < 4; ++t) {
    const int Lb = (wid * 4 + t) * 64;
    const int L = Lb + lane;
    const int row = L >> 3;
    const int jc = (L & 7) ^ (row & 7);
    GLDS(wb + (size_t)(128 + row) * 128 + jc * 16, &Ws1[Lb * 16]);
  }

  // ---- pack B fragments ONCE into registers (stride 320) ----
  long long B[4][4];
  float sq[4] = {0.f, 0.f, 0.f, 0.f};
#pragma unroll
  for (int ks = 0; ks < 4; ++ks) {
    const int cc = ks * 4 + quad;          // channel for this lane's k-chunk
    const float* xb = &Xs[cc * 320];       // [kd][hq][32] view
#pragma unroll
    for (int j = 0; j < 4; ++j) {
      const float* pB = xb + xoff[j];
      // k-elem order = (kd,kh,kw): strides kd=160, kh=32, kw=1 floats
      const float v0 = pB[0],   v1 = pB[1],   v2 = pB[32],  v3 = pB[33];
      const float v4 = pB[160], v5 = pB[161], v6 = pB[192], v7 = pB[193];
      sq[j] += v0*v0 + v1*v1 + v2*v2 + v3*v3 + v4*v4 + v5*v5 + v6*v6 + v7*v7;
      const unsigned lo = pk4_fp8(v0, v1, v2, v3);
      const unsigned hi = pk4_fp8(v4, v5, v6, v7);
      B[ks][j] = (long long)(((unsigned long long)hi << 32) | lo);
    }
  }
#pragma unroll
  for (int j = 0; j < 4; ++j) {
    sq[j] += __shfl_xor(sq[j], 16, 64);
    sq[j] += __shfl_xor(sq[j], 32, 64);
  }

  const int c16b = quad >> 1;
  const int hoff = (quad & 1) * 8;
  const int hw = lane >> 5;          // wave half (row selector)
  const int ll = lane & 31;          // lane within half
  const int nfull = (nrows == 124) ? 31 : 23;   // full-float4 lanes per strip

  // ---- ct loop: MFMA + 4-pass epilogue per 128-ch tile ----
#pragma unroll
  for (int ct = 0; ct < 4; ++ct) {
    if (ct > 0) VMC_BAR();           // Ws[ct&1] GLDS complete; stores fly on
    const u8* Wcur = (ct & 1) ? Ws1 : Ws0;

    f32x4 acc[4][4];
#pragma unroll
    for (int i = 0; i < 4; ++i)
#pragma unroll
      for (int j = 0; j < 4; ++j) acc[i][j] = (f32x4){0.f, 0.f, 0.f, 0.f};

#pragma unroll
    for (int ks = 0; ks < 4; ++ks) {
      long long a[4];
#pragma unroll
      for (int i = 0; i < 4; ++i) {
        const int rowA = wch * 64 + i * 16 + col;
        const int pa = (ks * 2 + c16b) ^ (rowA & 7);
        a[i] = *(const long long*)&Wcur[rowA * 128 + pa * 16 + hoff];
      }
#pragma unroll
      for (int i = 0; i < 4; ++i)
#pragma unroll
        for (int j = 0; j < 4; ++j)
          acc[i][j] = __builtin_amdgcn_mfma_f32_16x16x32_fp8_fp8(a[i], B[ks][j],
                                                                 acc[i][j], 0, 0, 0);
    }

    LGKM_BAR();   // Ws[ct&1] free; prior-iter Ep reads done (all lgkm = 0)

    // ---- refill the just-consumed buffer with ct+2 (flies under epilogue)
    if (ct < 2) {
      u8* Wn = (ct & 1) ? Ws1 : Ws0;
      const int cb = (ct + 2) * 128;
#pragma unroll
      for (int t = 0; t < 4; ++t) {
        const int Lb = (wid * 4 + t) * 64;
        const int L = Lb + lane;
        const int row = L >> 3;
        const int jc = (L & 7) ^ (row & 7);
        GLDS(wb + (size_t)(cb + row) * 128 + jc * 16, &Wn[Lb * 16]);
      }
    }

    // ---- transposed epilogue: 4 passes x 32 ch-rows (pass q = acc i) ----
    const int c0 = ct * 128;
#pragma unroll
    for (int q = 0; q < 4; ++q) {
      const int q2 = q >> 1, q1 = q & 1;
      // stage: 16 ds_write_b32 per thread into Ep[32][132]
#pragma unroll
      for (int r = 0; r < 4; ++r) {
        const int ch2 = wch * 16 + quad * 4 + r;            // Ep row
        const int chl = wch * 64 + q2 * 32 + q1 * 16 + quad * 4 + r;
        const float wsv = wsq[c0 + chl];
#pragma unroll
        for (int j = 0; j < 4; ++j)
          Ep[ch2 * 132 + rb[j]] = __expf(2.f * acc[q][j][r] - sq[j] - wsv);
      }
      LGKM_BAR();   // Ep visible to all waves; stores NOT drained

      // store: wave wid owns Ep rows [wid*8, wid*8+8); each iteration
      // stores TWO rows (one per wave-half), 16 B/lane dwordx4.
#pragma unroll
      for (int rr = 0; rr < 4; ++rr) {
        const int ch2 = wid * 8 + rr * 2 + hw;
        const int chl = (ch2 >> 4) * 64 + q2 * 32 + q1 * 16 + (ch2 & 15);
        float* ob = out + ((size_t)(nb * NCH + c0 + chl)) * P_OUT + tp0;
        if (ll < nfull) {
          const f4u v = *(const f4u*)&Ep[ch2 * 132 + 4 * ll];  // 16B-aligned LDS
          *(f4u*)(ob + 4 * ll) = v;                            // dword-aligned ok
        } else if (ll == 23 && nrows == 93) {
          ob[92] = Ep[ch2 * 132 + 92];                         // 93rd element
        }
      }
      if (q < 3) LGKM_BAR();   // Ep reads done -> next pass may overwrite
    }
  }
}

extern "C" void kernel_launch(void* const* d_in, const int* in_sizes, int n_in,
                              void* d_out, int out_size, void* d_ws, size_t ws_size,
                              hipStream_t stream) {
  const float* x = (const float*)d_in[0];
  const float* w = (const float*)d_in[1];
  float* out = (float*)d_out;
  char* ws = (char*)d_ws;
  // workspace: wb 512*128 fp8 = 65,536 B ; wsq 512*4 = 2,048 B
  u8* wb     = (u8*)ws;
  float* wsq = (float*)(ws + 65536);

  wprep_kernel<<<32, 256, 0, stream>>>(w, wb, wsq);
  gauss_fused_kernel<<<992, 256, 0, stream>>>(x, wb, wsq, out);
}

// Round 18
// 254.055 us; speedup vs baseline: 1.0260x; 1.0260x over previous
//
#include <hip/hip_runtime.h>

typedef unsigned char u8;
typedef float f32x4 __attribute__((ext_vector_type(4)));
typedef float f4u __attribute__((ext_vector_type(4), aligned(4)));  // dword-aligned float4

#define P_OUT 29791      // 31^3
#define NCH   512

// ---- pack 4 fp32 -> 4 fp8 e4m3 (RNE, OCP) ----
__device__ __forceinline__ unsigned pk4_fp8(float a, float b, float c, float d) {
  int v = __builtin_amdgcn_cvt_pk_fp8_f32(a, b, 0, false);   // low word
  v = __builtin_amdgcn_cvt_pk_fp8_f32(c, d, v, true);        // high word
  return (unsigned)v;
}

// ---- w-prep: 512 rows, 16 rows/block, 32 blocks ----
__global__ void wprep_kernel(const float* __restrict__ w,
                             u8* __restrict__ wb, float* __restrict__ wsq) {
  const int tid = threadIdx.x;
  const int g = blockIdx.x * 16 + (tid >> 4);  // 0..511
  const int c = tid & 15;
  const float4* wr = (const float4*)(w + g * 128 + c * 8);
  float4 f0 = wr[0], f1 = wr[1];
  float s = f0.x*f0.x + f0.y*f0.y + f0.z*f0.z + f0.w*f0.w
          + f1.x*f1.x + f1.y*f1.y + f1.z*f1.z + f1.w*f1.w;
#pragma unroll
  for (int m = 1; m < 16; m <<= 1) s += __shfl_xor(s, m, 64);
  uint2 pk;
  pk.x = pk4_fp8(f0.x, f0.y, f0.z, f0.w);
  pk.y = pk4_fp8(f1.x, f1.y, f1.z, f1.w);
  *(uint2*)(wb + g * 128 + c * 8) = pk;
  if (c == 0) wsq[g] = s;
}

// async global->LDS, 16 B per lane, lands at ldsbase + lane*16
#define GLDS(g, l) __builtin_amdgcn_global_load_lds(                         \
    (const __attribute__((address_space(1))) unsigned int*)(g),              \
    (__attribute__((address_space(3))) unsigned int*)(l), 16, 0, 0)

// lgkm-only barrier: orders LDS ops across waves WITHOUT draining vmcnt.
#define LGKM_BAR() do {                                                      \
    asm volatile("s_waitcnt lgkmcnt(0)\n\ts_barrier" ::: "memory");          \
    __builtin_amdgcn_sched_barrier(0);                                       \
  } while (0)

// counted-vmcnt barrier (T4): waits until <=16 VMEM ops outstanding.
// In-order retirement: the Ws prefetch has >=16 younger VMEM ops (the
// epilogue's 16 stores), so it is forced complete while the newest
// stores stay in flight. Stores are NEVER drained to 0.
#define VMC_BAR() do {                                                       \
    asm volatile("s_waitcnt vmcnt(16)\n\ts_barrier" ::: "memory");           \
    __builtin_amdgcn_sched_barrier(0);                                       \
  } while (0)

// ---- Fused unfold + GEMM, ct-loop pipeline + PING-PONG epilogue ----
// r16 base (248.0 us keeper) with ONE change: the epilogue runs 4 passes
// of 32 ch-rows through two Ep half-buffers, so store(q-1) (ds_read +
// global_store) issues IN THE SAME PHASE as stage(q) (exp + ds_write) --
// stores always have co-scheduled VALU/LDS work instead of sitting alone
// between barriers. Bars/ct: 5 vs r16's 4; SMEM unchanged (66,560 B,
// Ep 2 x [32][132] = same 33.8 KB union with Xs). Stores never drained.
// One block per (nb, d, hb): grid 992 = 8*124 bijective XCD chunking;
// Xs staged ONCE (stride-328 pad, r16 verbatim), B packed ONCE into 32
// VGPRs; ct = 0..3 with dbuf'd Ws (prefetch ct+2; completion via VMC_BAR).
__global__ __launch_bounds__(256, 2)
void gauss_fused_kernel(const float* __restrict__ x,
                        const u8* __restrict__ wb,
                        const float* __restrict__ wsq,
                        float* __restrict__ out) {
  __shared__ __align__(16) u8 SMEM[66560];
  u8* Ws0 = SMEM;                       // w tile buf 0, 16 KB
  u8* Ws1 = SMEM + 16384;               // w tile buf 1, 16 KB
  float* Xs = (float*)(SMEM + 32768);   // x slab [16c][328], 21 KB (prologue)
  float* Ep = (float*)(SMEM + 32768);   // epilogue 2 x [32][132] f32 (ct loop)

  const int bid = blockIdx.x;
  const int tile = (bid & 7) * 124 + (bid >> 3);   // bijective XCD chunking
  const unsigned nb = (unsigned)tile / 248u;       // 4 batches
  const unsigned r2 = (unsigned)tile - nb * 248u;
  const unsigned d  = r2 >> 3;                     // 31 d values
  const unsigned hb = r2 & 7;                      // 8 h-blocks, fastest
  const int h0 = hb * 4;
  const int nh = (h0 + 4 <= 31) ? 4 : (31 - h0);   // 4 (hb<7) or 3 (hb=7)
  const int nrows = nh * 31;                       // 124 or 93
  const int tp0 = d * 961 + h0 * 31;               // tile's base p

  const int tid = threadIdx.x;
  const int wid = tid >> 6;
  const int lane = tid & 63;
  const int quad = lane >> 4;
  const int col = lane & 15;
  const int wch = wid & 1;   // wave ch-half
  const int wp = wid >> 1;   // wave p-half

  // ---- stage Ws0 (ct=0, channels 0-127): 1024 swizzled chunks ----
#pragma unroll
  for (int t = 0; t < 4; ++t) {
    const int Lb = (wid * 4 + t) * 64;
    const int L = Lb + lane;
    const int row = L >> 3;
    const int jc = (L & 7) ^ (row & 7);
    GLDS(wb + (size_t)row * 128 + jc * 16, &Ws0[Lb * 16]);
  }

  // ---- stage x slab [16c][82 chunks]: 80 data + 2 pad (r16 verbatim) ----
#pragma unroll
  for (int t = 0; t < 6; ++t) {
    if (t < 5 || wid == 0) {
      const int Lb = t * 256 + wid * 64;
      const int L = Lb + lane;               // 0..1343
      unsigned c = (unsigned)L / 82u;
      if (c > 15u) c = 15u;
      unsigned rc = (unsigned)L - c * 82u;
      if (rc > 79u) rc = 79u;
      const unsigned kd = rc / 40u;
      const unsigned rr = rc - kd * 40u;
      const unsigned hq = rr >> 3;
      const int jc = (int)(rr & 7u);
      const int hg = h0 + (int)hq;
      const int hcl = (hg < 31) ? hg : 31;
      GLDS(x + (((size_t)(nb * 16 + c)) << 15) + (d + kd) * 1024 + hcl * 32 + jc * 4,
           &Xs[Lb * 4]);
    }
  }

  // ---- per-lane p-row decode (hides under GLDS flight) ----
  int rb[4];
  int xoff[4];
#pragma unroll
  for (int j = 0; j < 4; ++j) {
    rb[j] = wp * 64 + j * 16 + col;
    const unsigned rc = (unsigned)((rb[j] < nrows) ? rb[j] : (nrows - 1));
    const unsigned hh = rc / 31u;
    const unsigned wv = rc - hh * 31u;
    xoff[j] = (int)(hh * 32 + wv);
  }

  __syncthreads();   // block start: drains Ws0 + Xs (no stores pending)

  // ---- prefetch Ws1 (ct=1, channels 128-255); flies under the pack ----
#pragma unroll
  for (int t = 0; t < 4; ++t) {
    const int Lb = (wid * 4 + t) * 64;
    const int L = Lb + lane;
    const int row = L >> 3;
    const int jc = (L & 7) ^ (row & 7);
    GLDS(wb + (size_t)(128 + row) * 128 + jc * 16, &Ws1[Lb * 16]);
  }

  // ---- pack B fragments ONCE into registers (stride 328, r16 verbatim) ----
  long long B[4][4];
  float sq[4] = {0.f, 0.f, 0.f, 0.f};
#pragma unroll
  for (int ks = 0; ks < 4; ++ks) {
    const int cc = ks * 4 + quad;          // channel for this lane's k-chunk
    const float* xb = &Xs[cc * 328];       // [kd][hq][32] view, padded stride
#pragma unroll
    for (int j = 0; j < 4; ++j) {
      const float* pB = xb + xoff[j];
      // k-elem order = (kd,kh,kw): strides kd=160, kh=32, kw=1 floats
      const float v0 = pB[0],   v1 = pB[1],   v2 = pB[32],  v3 = pB[33];
      const float v4 = pB[160], v5 = pB[161], v6 = pB[192], v7 = pB[193];
      sq[j] += v0*v0 + v1*v1 + v2*v2 + v3*v3 + v4*v4 + v5*v5 + v6*v6 + v7*v7;
      const unsigned lo = pk4_fp8(v0, v1, v2, v3);
      const unsigned hi = pk4_fp8(v4, v5, v6, v7);
      B[ks][j] = (long long)(((unsigned long long)hi << 32) | lo);
    }
  }
#pragma unroll
  for (int j = 0; j < 4; ++j) {
    sq[j] += __shfl_xor(sq[j], 16, 64);
    sq[j] += __shfl_xor(sq[j], 32, 64);
  }

  const int c16b = quad >> 1;
  const int hoff = (quad & 1) * 8;
  const int hw = lane >> 5;          // wave half (row selector)
  const int ll = lane & 31;          // lane within half
  const int nfull = (nrows == 124) ? 31 : 23;   // full-float4 lanes per strip

  // ---- ct loop: MFMA + ping-pong epilogue per 128-ch tile ----
#pragma unroll
  for (int ct = 0; ct < 4; ++ct) {
    if (ct > 0) VMC_BAR();           // Ws[ct&1] GLDS complete; stores fly on
    const u8* Wcur = (ct & 1) ? Ws1 : Ws0;

    f32x4 acc[4][4];
#pragma unroll
    for (int i = 0; i < 4; ++i)
#pragma unroll
      for (int j = 0; j < 4; ++j) acc[i][j] = (f32x4){0.f, 0.f, 0.f, 0.f};

#pragma unroll
    for (int ks = 0; ks < 4; ++ks) {
      long long a[4];
#pragma unroll
      for (int i = 0; i < 4; ++i) {
        const int rowA = wch * 64 + i * 16 + col;
        const int pa = (ks * 2 + c16b) ^ (rowA & 7);
        a[i] = *(const long long*)&Wcur[rowA * 128 + pa * 16 + hoff];
      }
#pragma unroll
      for (int i = 0; i < 4; ++i)
#pragma unroll
        for (int j = 0; j < 4; ++j)
          acc[i][j] = __builtin_amdgcn_mfma_f32_16x16x32_fp8_fp8(a[i], B[ks][j],
                                                                 acc[i][j], 0, 0, 0);
    }

    LGKM_BAR();   // Ws[ct&1] free; prior-ct Ep reads all drained

    // ---- refill the just-consumed buffer with ct+2 (flies under epilogue)
    if (ct < 2) {
      u8* Wn = (ct & 1) ? Ws1 : Ws0;
      const int cb = (ct + 2) * 128;
#pragma unroll
      for (int t = 0; t < 4; ++t) {
        const int Lb = (wid * 4 + t) * 64;
        const int L = Lb + lane;
        const int row = L >> 3;
        const int jc = (L & 7) ^ (row & 7);
        GLDS(wb + (size_t)(cb + row) * 128 + jc * 16, &Wn[Lb * 16]);
      }
    }

    // ---- ping-pong epilogue: pass q stages Ep[q&1] while q-1 stores ----
    const int c0 = ct * 128;
    // stage pass 0
    {
      float* Epd = Ep;                 // Ep[0]
#pragma unroll
      for (int r = 0; r < 4; ++r) {
        const int ch2 = wch * 16 + quad * 4 + r;
        const int chl = wch * 64 + quad * 4 + r;        // q=0: q2=0,q1=0
        const float wsv = wsq[c0 + chl];
#pragma unroll
        for (int j = 0; j < 4; ++j)
          Epd[ch2 * 132 + rb[j]] = __expf(2.f * acc[0][j][r] - sq[j] - wsv);
      }
    }
    LGKM_BAR();

#pragma unroll
    for (int q = 1; q < 4; ++q) {
      // store pass q-1 (ds_read + global_store)...
      {
        const int qs = q - 1;
        const float* Eps = Ep + (qs & 1) * 4224;
        const int s2 = qs >> 1, s1 = qs & 1;
#pragma unroll
        for (int rr = 0; rr < 4; ++rr) {
          const int ch2 = wid * 8 + rr * 2 + hw;
          const int chl = (ch2 >> 4) * 64 + s2 * 32 + s1 * 16 + (ch2 & 15);
          float* ob = out + ((size_t)(nb * NCH + c0 + chl)) * P_OUT + tp0;
          if (ll < nfull) {
            const f4u v = *(const f4u*)&Eps[ch2 * 132 + 4 * ll];
            *(f4u*)(ob + 4 * ll) = v;
          } else if (ll == 23 && nrows == 93) {
            ob[92] = Eps[ch2 * 132 + 92];
          }
        }
      }
      // ...concurrently stage pass q (exp + ds_write into the other half)
      {
        float* Epd = Ep + (q & 1) * 4224;
        const int q2 = q >> 1, q1 = q & 1;
#pragma unroll
        for (int r = 0; r < 4; ++r) {
          const int ch2 = wch * 16 + quad * 4 + r;
          const int chl = wch * 64 + q2 * 32 + q1 * 16 + quad * 4 + r;
          const float wsv = wsq[c0 + chl];
#pragma unroll
          for (int j = 0; j < 4; ++j)
            Epd[ch2 * 132 + rb[j]] = __expf(2.f * acc[q][j][r] - sq[j] - wsv);
        }
      }
      LGKM_BAR();   // stage-q visible; pass q-1's Ep reads drained
    }

    // store pass 3 (no trailing barrier; flows into next ct's VMC_BAR)
    {
      const float* Eps = Ep + 4224;    // Ep[1] (q=3)
#pragma unroll
      for (int rr = 0; rr < 4; ++rr) {
        const int ch2 = wid * 8 + rr * 2 + hw;
        const int chl = (ch2 >> 4) * 64 + 32 + 16 + (ch2 & 15);  // q2=1,q1=1
        float* ob = out + ((size_t)(nb * NCH + c0 + chl)) * P_OUT + tp0;
        if (ll < nfull) {
          const f4u v = *(const f4u*)&Eps[ch2 * 132 + 4 * ll];
          *(f4u*)(ob + 4 * ll) = v;
        } else if (ll == 23 && nrows == 93) {
          ob[92] = Eps[ch2 * 132 + 92];
        }
      }
    }
  }
}

extern "C" void kernel_launch(void* const* d_in, const int* in_sizes, int n_in,
                              void* d_out, int out_size, void* d_ws, size_t ws_size,
                              hipStream_t stream) {
  const float* x = (const float*)d_in[0];
  const float* w = (const float*)d_in[1];
  float* out = (float*)d_out;
  char* ws = (char*)d_ws;
  // workspace: wb 512*128 fp8 = 65,536 B ; wsq 512*4 = 2,048 B
  u8* wb     = (u8*)ws;
  float* wsq = (float*)(ws + 65536);

  wprep_kernel<<<32, 256, 0, stream>>>(w, wb, wsq);
  gauss_fused_kernel<<<992, 256, 0, stream>>>(x, wb, wsq, out);
}